// Round 2
// baseline (276.991 us; speedup 1.0000x reference)
//
#include <hip/hip_runtime.h>
#include <hip/hip_bf16.h>
#include <stdint.h>
#include <string.h>

// B=2, S=2048, D_MODEL=1024, H=16, Dh=64
#define SEQ   2048
#define DM    1024
#define NH    16
#define NB    2

typedef __attribute__((ext_vector_type(8))) short bf16x8;
typedef __attribute__((ext_vector_type(4))) float f32x4;
typedef unsigned short u16;
typedef unsigned int   u32;

__device__ __forceinline__ u16 f2bf(float f) {
    u32 u = __float_as_uint(f);
    u += 0x7FFF + ((u >> 16) & 1);   // RNE
    return (u16)(u >> 16);
}
__device__ __forceinline__ u32 pk2bf(float a, float b) {
    __hip_bfloat162 p = __float22bfloat162_rn(make_float2(a, b));
    u32 u; memcpy(&u, &p, 4); return u;
}
__device__ __forceinline__ float fexp2(float x) {
#if __has_builtin(__builtin_amdgcn_exp2f)
    return __builtin_amdgcn_exp2f(x);
#else
    return exp2f(x);
#endif
}
// exp2 with mask folded in: keep-bit (from inverted mask word) sign-extended
// and ANDed into the result. masked -> exactly 0.0f (== exp2(-1e9) path).
__device__ __forceinline__ float mask_exp2(float s, u32 lsel, int pos) {
#if __has_builtin(__builtin_amdgcn_sbfe)
    u32 keep = (u32)__builtin_amdgcn_sbfe((int)lsel, pos, 1);
#else
    u32 keep = (u32)((int)(lsel << (31 - pos)) >> 31);
#endif
    return __uint_as_float(__float_as_uint(fexp2(s)) & keep);
}
// async global->LDS, 16B/lane; LDS dest = wave-uniform base + lane*16
__device__ __forceinline__ void gl_lds16(const void* g, void* l) {
    __builtin_amdgcn_global_load_lds(
        (const __attribute__((address_space(1))) u32*)g,
        (__attribute__((address_space(3))) u32*)l, 16, 0, 0);
}
// Raw barrier WITHOUT vmcnt(0) drain: wait until only N newest VMEM ops
// remain in flight, then s_barrier. "memory" clobber pins ordering.
__device__ __forceinline__ void wbar_vm3() { asm volatile("s_waitcnt vmcnt(3)\ns_barrier" ::: "memory"); }
__device__ __forceinline__ void wbar_vm4() { asm volatile("s_waitcnt vmcnt(4)\ns_barrier" ::: "memory"); }
__device__ __forceinline__ void vm_drain() { asm volatile("s_waitcnt vmcnt(0)" ::: "memory"); }

// ---------------------------------------------------------------------------
// fp32 -> bf16 bulk convert; Wq pre-scaled by 0.125*log2(e) (exp2 domain).
// ---------------------------------------------------------------------------
struct CvtArgs {
    const float* s[7];
    u16* d[7];
    float scale[7];
    int start[8];
};
__global__ __launch_bounds__(256) void cvt_kernel(CvtArgs a) {
    int bid = blockIdx.x;
    int seg = 0;
#pragma unroll
    for (int i = 1; i < 7; ++i) if (bid >= a.start[i]) seg = i;
    float sc = a.scale[seg];
    size_t base = (size_t)(bid - a.start[seg]) * 2048 + threadIdx.x * 8;
    const float4* s4 = (const float4*)(a.s[seg] + base);
    float4 x = s4[0], y = s4[1];
    u32 r[4];
    r[0] = pk2bf(x.x*sc, x.y*sc); r[1] = pk2bf(x.z*sc, x.w*sc);
    r[2] = pk2bf(y.x*sc, y.y*sc); r[3] = pk2bf(y.z*sc, y.w*sc);
    *(uint4*)(a.d[seg] + base) = *(uint4*)r;
}

// ---------------------------------------------------------------------------
// mask -> bits; word = bits[(b*2048+m)*64 + n/32]
// ---------------------------------------------------------------------------
__global__ void maskpack_kernel(const int* __restrict__ mask,
                                unsigned int* __restrict__ bits) {
    int gid = blockIdx.x * 256 + threadIdx.x;
    int m = mask[gid];
    unsigned long long bal = __ballot(m != 0);
    int lane = threadIdx.x & 63;
    if (lane == 0)       bits[gid >> 5] = (u32)(bal & 0xFFFFFFFFull);
    else if (lane == 32) bits[gid >> 5] = (u32)(bal >> 32);
}

// ---------------------------------------------------------------------------
// bf16 GEMM: Y[r][c] = sum_k A[r][k]*B[c][k], K=1024, BK=32.
// Triple-buffered LDS, prefetch distance 2, raw-barrier pipeline (no vmcnt(0)
// drains inside the loop). XOR swizzle (4 chunks/row) for conflict-free b128.
// RT=4: 128x128 tile; RT=2: 64x128. 256 threads, waves 2x2.
// mode 0: bf16 (B,H,S,64); mode 1: bf16 (B,H,64,S); mode 2: fp32 row-major.
// ---------------------------------------------------------------------------
template<int RT>
__device__ __forceinline__ void gemm_body(const u16* __restrict__ A,
                                          const u16* __restrict__ Bm,
                                          void* __restrict__ Y,
                                          int rtile, int ctile, int mode,
                                          u16* sA, u16* sB) {
    constexpr int ABUF = RT * 32 * 32;          // u16 per A buffer
    constexpr int BBUF = 128 * 32;
    const int tid  = threadIdx.x;
    const int wv   = tid >> 6, lane = tid & 63;
    const int quad = lane >> 4, ln = lane & 15;
    const int wr   = wv >> 1,  wc  = wv & 1;

    const int lr4 = lane >> 2;                          // row in 16-row shot
    const int lcc = ((lane & 3) ^ ((lane >> 3) & 3)) * 8;  // swizzled src col

    const u16* gA[RT/2]; u16* lA[RT/2];
#pragma unroll
    for (int s = 0; s < RT/2; ++s) {
        int seg = wv * (RT/2) + s;
        gA[s] = A + (size_t)(rtile * (RT*32) + seg*16 + lr4) * 1024 + lcc;
        lA[s] = sA + seg * 512;
    }
    const u16* gB[2]; u16* lB[2];
#pragma unroll
    for (int s = 0; s < 2; ++s) {
        int seg = wv * 2 + s;
        gB[s] = Bm + (size_t)(ctile * 128 + seg*16 + lr4) * 1024 + lcc;
        lB[s] = sB + seg * 512;
    }

    f32x4 acc[RT][4];
#pragma unroll
    for (int i = 0; i < RT; ++i)
#pragma unroll
        for (int j = 0; j < 4; ++j) acc[i][j] = (f32x4){0.f,0.f,0.f,0.f};

    const int c0 = (quad ^ ((ln >> 1) & 3)) * 8;

    // prologue: stage kt=0 -> buf0, kt=1 -> buf1
#pragma unroll
    for (int s = 0; s < RT/2; ++s) gl_lds16(gA[s], lA[s]);
#pragma unroll
    for (int s = 0; s < 2; ++s)    gl_lds16(gB[s], lB[s]);
#pragma unroll
    for (int s = 0; s < RT/2; ++s) gl_lds16(gA[s] + 32, lA[s] + ABUF);
#pragma unroll
    for (int s = 0; s < 2; ++s)    gl_lds16(gB[s] + 32, lB[s] + BBUF);

    int bc = 0, bp = 2;
    for (int kt = 0; kt < 32; ++kt) {
        if (RT == 4) wbar_vm4(); else wbar_vm3();   // drain kt's loads only
        int pk = (kt + 2) & 31;                     // wrap keeps waitcnt uniform
#pragma unroll
        for (int s = 0; s < RT/2; ++s) gl_lds16(gA[s] + pk*32, lA[s] + bp*ABUF);
#pragma unroll
        for (int s = 0; s < 2; ++s)    gl_lds16(gB[s] + pk*32, lB[s] + bp*BBUF);

        const u16* sAb = sA + bc * ABUF;
        const u16* sBb = sB + bc * BBUF;
        bf16x8 af[RT], bfr[4];
#pragma unroll
        for (int rt = 0; rt < RT; ++rt)
            af[rt] = *(const bf16x8*)(sAb + (wr*(RT*16) + rt*16 + ln) * 32 + c0);
#pragma unroll
        for (int ct = 0; ct < 4; ++ct)
            bfr[ct] = *(const bf16x8*)(sBb + (wc*64 + ct*16 + ln) * 32 + c0);
#pragma unroll
        for (int rt = 0; rt < RT; ++rt)
#pragma unroll
            for (int ct = 0; ct < 4; ++ct)
                acc[rt][ct] = __builtin_amdgcn_mfma_f32_16x16x32_bf16(
                    af[rt], bfr[ct], acc[rt][ct], 0, 0, 0);

        bc = (bc == 2) ? 0 : bc + 1;
        bp = (bp == 2) ? 0 : bp + 1;
    }
    vm_drain();   // in-flight gl_lds must not land after LDS is reallocated

#pragma unroll
    for (int rt = 0; rt < RT; ++rt) {
#pragma unroll
        for (int ct = 0; ct < 4; ++ct) {
#pragma unroll
            for (int i = 0; i < 4; ++i) {
                int R = rtile*(RT*32) + wr*(RT*16) + rt*16 + quad*4 + i;
                int C = ctile*128 + wc*64 + ct*16 + ln;
                float val = acc[rt][ct][i];
                if (mode == 0) {
                    int b = R >> 11, s = R & 2047, h = C >> 6, d = C & 63;
                    ((u16*)Y)[((size_t)((b*NH + h) * SEQ + s) << 6) + d] = f2bf(val);
                } else if (mode == 1) {
                    int h = R >> 6, d = R & 63, b = C >> 11, n = C & 2047;
                    ((u16*)Y)[((size_t)((b*NH + h) * 64 + d) << 11) + n] = f2bf(val);
                } else {
                    ((float*)Y)[(size_t)R * 1024 + C] = val;
                }
            }
        }
    }
}

struct QKVArgs { const u16* A[3]; const u16* B[3]; u16* Y[3]; };

__global__ __launch_bounds__(256) void gemm_qkv(QKVArgs g) {
    __shared__ u16 sA[3 * 128 * 32];
    __shared__ u16 sB[3 * 128 * 32];
    int z = blockIdx.z;
    if (z == 2)
        gemm_body<4>(g.A[2], g.B[2], g.Y[2], blockIdx.y, blockIdx.x, 1, sA, sB);
    else
        gemm_body<4>(g.A[z], g.B[z], g.Y[z], blockIdx.x, blockIdx.y, 0, sA, sB);
}

__global__ __launch_bounds__(256) void gemm_out(const u16* __restrict__ A,
                                                const u16* __restrict__ Bm,
                                                float* __restrict__ Y) {
    __shared__ u16 sA[3 * 64 * 32];
    __shared__ u16 sB[3 * 128 * 32];
    gemm_body<2>(A, Bm, Y, blockIdx.x, blockIdx.y, 2, sA, sB);
}

// ---------------------------------------------------------------------------
// Flash attention v5: 8 waves = 4 m-groups x 2 n-halves.
// v4 was LDS-read-throughput bound (~70% of wall): every wave read the FULL
// 64x64 K and V tile regardless of rows owned. Now each wave owns 32 m-rows
// but only a 32-n half-slice: K reads 8KB->4KB, V 8KB->4KB per wave per iter,
// P roundtrip k=32 = exactly one A-fragment (and lsum is 1 MFMA per mt).
// Per-CU LDS reads/iter: 288KB -> 160KB. O/lsum are additive over n ->
// one-time LDS combine epilogue between n-half partners.
// LDS 67584B unchanged -> 2 blocks/CU; launch_bounds(512,4) pins VGPR<=128.
// ---------------------------------------------------------------------------
__global__ __launch_bounds__(512, 4) void attn_kernel(
    const u16* __restrict__ qw,
    const u16* __restrict__ kw,
    const u16* __restrict__ vt,
    const u32* __restrict__ mbits,
    u16* __restrict__ ctx) {

    constexpr int RSD = 18;                 // sP row stride in dwords (36 u16)
    __shared__ __align__(16) char smem[67584];
    u16* sK  = (u16*)smem;                  // 3 bufs x 8KB
    u16* sV  = (u16*)(smem + 24576);        // 3 bufs x 8KB
    u32* sPd = (u32*)(smem + 49152);        // 8 waves x 32 rows x 18 dw = 18KB

    const int mtile = blockIdx.x;           // 0..15 (128 m-rows each)
    const int bh    = blockIdx.y;           // 0..31
    const int b     = bh >> 4;
    const int tid   = threadIdx.x;
    const int wv    = tid >> 6, lane = tid & 63;
    const int quad  = lane >> 4, ln = lane & 15;
    const int g     = wv >> 2;              // n-half (0: n 0..31, 1: n 32..63)
    const int w2    = wv & 3;               // m-group (32 rows each)
    const int m0    = mtile * 128;

    const size_t hbase = (size_t)bh * SEQ * 64;

    // Q fragments (B operand of S^T): rows m = m0 + w2*32 + mt*16 + ln
    bf16x8 qf[2][2];
#pragma unroll
    for (int mt = 0; mt < 2; ++mt) {
        const u16* qp = qw + hbase + (size_t)(m0 + w2*32 + mt*16 + ln) * 64 + quad*8;
        qf[mt][0] = *(const bf16x8*)(qp);
        qf[mt][1] = *(const bf16x8*)(qp + 32);
    }

    f32x4 o[2][4], lsum[2];
#pragma unroll
    for (int mt = 0; mt < 2; ++mt) {
        lsum[mt] = (f32x4){0.f,0.f,0.f,0.f};
#pragma unroll
        for (int j = 0; j < 4; ++j) o[mt][j] = (f32x4){0.f,0.f,0.f,0.f};
    }

    bf16x8 ones;
#pragma unroll
    for (int i = 0; i < 8; ++i) ones[i] = (short)0x3F80;   // bf16 1.0

    // mask: word g of each row's 2-word tile record
    const u32* mrow[2];
#pragma unroll
    for (int mt = 0; mt < 2; ++mt)
        mrow[mt] = mbits + (size_t)(b*SEQ + m0 + w2*32 + mt*16 + ln) * 64 + g;

    // K/V staging (block-wide, all 8 waves): one 16B shot per thread per tile
    const int lr = lane >> 3;
    const int lc = (lane & 7) ^ lr;                      // XOR-swizzled chunk
    const u16* gK = kw + hbase + (size_t)(wv*8 + lr) * 64 + lc*8;
    const u16* gV = vt + hbase + (size_t)(wv*8 + lr) * SEQ + lc*8;
    u16* lK = sK + wv * 512;
    u16* lV = sV + wv * 512;

    const int c0  = (quad ^ (ln & 7)) * 8;               // K d-chunk quad
    const int c0v = (((g*4 + quad) ^ (ln & 7))) * 8;     // V n-chunk g*4+quad
    u32* sPw = sPd + wv * 32 * RSD;

    // prologue: tiles 0 and 1 -> bufs 0, 1 (4 VMEM ops per tile: K,V,m0,m1)
    gl_lds16(gK, lK);
    gl_lds16(gV, lV);
    u32 wwA[2], wwB[2], wwC[2];
#pragma unroll
    for (int mt = 0; mt < 2; ++mt) wwA[mt] = mrow[mt][0];
    gl_lds16(gK + 4096, lK + 4096);
    gl_lds16(gV + 64,   lV + 4096);
#pragma unroll
    for (int mt = 0; mt < 2; ++mt) wwB[mt] = mrow[mt][2];

    int bc = 0, bp = 2;
    for (int nt = 0; nt < SEQ / 64; ++nt) {
        wbar_vm4();                          // drain tile nt's 4 loads only
        int pidx = (nt + 2) & 31;            // wrap keeps waitcnt uniform
        gl_lds16(gK + (size_t)pidx * 4096, lK + bp*4096);
        gl_lds16(gV + pidx * 64,           lV + bp*4096);
#pragma unroll
        for (int mt = 0; mt < 2; ++mt) wwC[mt] = mrow[mt][pidx*2];

        const u16* sKb = sK + bc * 4096;
        const u16* sVb = sV + bc * 4096;

        // S^T = K Q^T over this wave's n-half: rows n = g*32 + ct2*16 + ln
        f32x4 s4[2][2];
#pragma unroll
        for (int ct2 = 0; ct2 < 2; ++ct2) {
            const u16* kp = sKb + (g*32 + ct2*16 + ln) * 64;
            bf16x8 k0 = *(const bf16x8*)(kp + c0);
            bf16x8 k1 = *(const bf16x8*)(kp + (c0 ^ 32));
#pragma unroll
            for (int mt = 0; mt < 2; ++mt) {
                f32x4 z = (f32x4){0.f, 0.f, 0.f, 0.f};
                z = __builtin_amdgcn_mfma_f32_16x16x32_bf16(k0, qf[mt][0], z, 0, 0, 0);
                z = __builtin_amdgcn_mfma_f32_16x16x32_bf16(k1, qf[mt][1], z, 0, 0, 0);
                s4[mt][ct2] = z;
            }
        }

        // p = exp2(s) & keep-mask; packed b64 writes into wave-private sP
#pragma unroll
        for (int mt = 0; mt < 2; ++mt) {
            u32 l = ~(wwA[mt] >> (quad * 4));
#pragma unroll
            for (int ct2 = 0; ct2 < 2; ++ct2) {
                float p[4];
#pragma unroll
                for (int i = 0; i < 4; ++i)
                    p[i] = mask_exp2(s4[mt][ct2][i], l, ct2 * 16 + i);
                uint2 pk;
                pk.x = pk2bf(p[0], p[1]);
                pk.y = pk2bf(p[2], p[3]);
                *(uint2*)(sPw + (mt*16 + ln) * RSD + ct2*8 + quad*2) = pk;
            }
        }
        // no barrier: sP slab is wave-private (in-wave lgkm ordering)

        // O += P V ; lsum += P * ones   (k = 32 = one A-fragment)
#pragma unroll
        for (int mt = 0; mt < 2; ++mt) {
            uint4 praw = *(const uint4*)(sPw + (mt*16 + ln) * RSD + quad*4);
            bf16x8 pf; memcpy(&pf, &praw, 16);
            lsum[mt] = __builtin_amdgcn_mfma_f32_16x16x32_bf16(pf, ones, lsum[mt], 0, 0, 0);
#pragma unroll
            for (int ct = 0; ct < 4; ++ct) {
                bf16x8 vf = *(const bf16x8*)(sVb + (ct*16 + ln) * 64 + c0v);
                o[mt][ct] = __builtin_amdgcn_mfma_f32_16x16x32_bf16(pf, vf, o[mt][ct], 0, 0, 0);
            }
        }

        wwA[0] = wwB[0]; wwA[1] = wwB[1];
        wwB[0] = wwC[0]; wwB[1] = wwC[1];
        bc = (bc == 2) ? 0 : bc + 1;
        bp = (bp == 2) ? 0 : bp + 1;
    }
    vm_drain();       // in-flight gl_lds must not land after LDS is reallocated
    __syncthreads();  // all waves done with sK/sV before reuse as sO

    // n-half combine: g==1 writes partial O (stride-65 pad) + lsum; g==0 sums,
    // normalizes, stores. One-time cost.
    float* sO  = (float*)smem;              // 128 x 65 floats = 33280 B
    float* sLs = (float*)(smem + 33280);    // 128 floats
    if (g == 1) {
#pragma unroll
        for (int mt = 0; mt < 2; ++mt)
#pragma unroll
            for (int i = 0; i < 4; ++i) {
                int lm = w2*32 + mt*16 + quad*4 + i;
                sLs[lm] = lsum[mt][i];
#pragma unroll
                for (int ct = 0; ct < 4; ++ct)
                    sO[lm*65 + ct*16 + ln] = o[mt][ct][i];
            }
    }
    __syncthreads();
    if (g == 0) {
#pragma unroll
        for (int mt = 0; mt < 2; ++mt)
#pragma unroll
            for (int i = 0; i < 4; ++i) {
                int lm = w2*32 + mt*16 + quad*4 + i;
                float inv = 1.f / (lsum[mt][i] + sLs[lm]);
                int m = m0 + lm;
                size_t base = ((size_t)(b * SEQ + m) << 10) + (bh & 15) * 64;
#pragma unroll
                for (int ct = 0; ct < 4; ++ct)
                    ctx[base + ct*16 + ln] =
                        f2bf((o[mt][ct][i] + sO[lm*65 + ct*16 + ln]) * inv);
            }
    }
}

// ---------------------------------------------------------------------------
extern "C" void kernel_launch(void* const* d_in, const int* in_sizes, int n_in,
                              void* d_out, int out_size, void* d_ws, size_t ws_size,
                              hipStream_t stream) {
    const float* q    = (const float*)d_in[0];
    const float* k    = (const float*)d_in[1];
    const float* v    = (const float*)d_in[2];
    const int*   mask = (const int*)d_in[3];
    const float* Wq   = (const float*)d_in[4];
    const float* Wk   = (const float*)d_in[5];
    const float* Wv   = (const float*)d_in[6];
    const float* Wo   = (const float*)d_in[7];
    float* out = (float*)d_out;

    char* ws = (char*)d_ws;
    const size_t SZH = (size_t)NB * SEQ * DM * 2;       // 8 MiB
    const size_t SZW = (size_t)DM * DM * 2;             // 2 MiB
    u16* qw   = (u16*)(ws);
    u16* kw   = (u16*)(ws + SZH);
    u16* vt   = (u16*)(ws + 2*SZH);
    u16* ctx  = (u16*)(ws + 3*SZH);
    u16* vb   = ctx;                                    // v bf16 (dead before ctx)
    u32* mbits= (u32*)(ws + 4*SZH);                     // 1 MiB
    u16* qb   = (u16*)(ws + 4*SZH + (1u<<20));
    u16* kb   = (u16*)(ws + 4*SZH + (1u<<20) + SZH);
    u16* Wqb  = (u16*)(ws + 4*SZH + (1u<<20) + 2*SZH);
    u16* Wkb  = (u16*)((char*)Wqb + SZW);
    u16* Wvb  = (u16*)((char*)Wqb + 2*SZW);
    u16* Wob  = (u16*)((char*)Wqb + 3*SZW);

    const float CSC = 0.18033688011112042f;             // 0.125 * log2(e)

    CvtArgs ca;
    ca.s[0]=q;  ca.d[0]=qb;  ca.scale[0]=1.f;
    ca.s[1]=k;  ca.d[1]=kb;  ca.scale[1]=1.f;
    ca.s[2]=v;  ca.d[2]=vb;  ca.scale[2]=1.f;
    ca.s[3]=Wq; ca.d[3]=Wqb; ca.scale[3]=CSC;
    ca.s[4]=Wk; ca.d[4]=Wkb; ca.scale[4]=1.f;
    ca.s[5]=Wv; ca.d[5]=Wvb; ca.scale[5]=1.f;
    ca.s[6]=Wo; ca.d[6]=Wob; ca.scale[6]=1.f;
    int st[8] = {0, 2048, 4096, 6144, 6656, 7168, 7680, 8192};
    for (int i = 0; i < 8; ++i) ca.start[i] = st[i];
    cvt_kernel<<<dim3(8192), dim3(256), 0, stream>>>(ca);

    maskpack_kernel<<<dim3(NB*SEQ*SEQ/256), dim3(256), 0, stream>>>(mask, mbits);

    QKVArgs ga;
    ga.A[0]=qb;  ga.B[0]=Wqb; ga.Y[0]=qw;
    ga.A[1]=kb;  ga.B[1]=Wkb; ga.Y[1]=kw;
    ga.A[2]=Wvb; ga.B[2]=vb;  ga.Y[2]=vt;
    gemm_qkv<<<dim3(32, 8, 3), dim3(256), 0, stream>>>(ga);

    attn_kernel<<<dim3(SEQ/128, NB*NH), dim3(512), 0, stream>>>(qw, kw, vt, mbits, ctx);

    gemm_out<<<dim3(64, 8), dim3(256), 0, stream>>>(ctx, Wob, out);
}

// Round 3
// 265.726 us; speedup vs baseline: 1.0424x; 1.0424x over previous
//
#include <hip/hip_runtime.h>
#include <hip/hip_bf16.h>
#include <stdint.h>
#include <string.h>

// B=2, S=2048, D_MODEL=1024, H=16, Dh=64
#define SEQ   2048
#define DM    1024
#define NH    16
#define NB    2

typedef __attribute__((ext_vector_type(8))) short bf16x8;
typedef __attribute__((ext_vector_type(4))) float f32x4;
typedef unsigned short u16;
typedef unsigned int   u32;

__device__ __forceinline__ u16 f2bf(float f) {
    u32 u = __float_as_uint(f);
    u += 0x7FFF + ((u >> 16) & 1);   // RNE
    return (u16)(u >> 16);
}
__device__ __forceinline__ u32 pk2bf(float a, float b) {
    __hip_bfloat162 p = __float22bfloat162_rn(make_float2(a, b));
    u32 u; memcpy(&u, &p, 4); return u;
}
__device__ __forceinline__ float fexp2(float x) {
#if __has_builtin(__builtin_amdgcn_exp2f)
    return __builtin_amdgcn_exp2f(x);
#else
    return exp2f(x);
#endif
}
// exp2 with mask folded in: keep-bit (from inverted mask word) sign-extended
// and ANDed into the result. masked -> exactly 0.0f (== exp2(-1e9) path).
__device__ __forceinline__ float mask_exp2(float s, u32 lsel, int pos) {
#if __has_builtin(__builtin_amdgcn_sbfe)
    u32 keep = (u32)__builtin_amdgcn_sbfe((int)lsel, pos, 1);
#else
    u32 keep = (u32)((int)(lsel << (31 - pos)) >> 31);
#endif
    return __uint_as_float(__float_as_uint(fexp2(s)) & keep);
}
// async global->LDS, 16B/lane; LDS dest = wave-uniform base + lane*16
__device__ __forceinline__ void gl_lds16(const void* g, void* l) {
    __builtin_amdgcn_global_load_lds(
        (const __attribute__((address_space(1))) u32*)g,
        (__attribute__((address_space(3))) u32*)l, 16, 0, 0);
}
// Raw barrier WITHOUT vmcnt(0) drain: wait until only N newest VMEM ops
// remain in flight, then s_barrier. "memory" clobber pins ordering.
__device__ __forceinline__ void wbar_vm2() { asm volatile("s_waitcnt vmcnt(2)\ns_barrier" ::: "memory"); }
__device__ __forceinline__ void wbar_vm3() { asm volatile("s_waitcnt vmcnt(3)\ns_barrier" ::: "memory"); }
__device__ __forceinline__ void wbar_vm4() { asm volatile("s_waitcnt vmcnt(4)\ns_barrier" ::: "memory"); }
__device__ __forceinline__ void vm_drain() { asm volatile("s_waitcnt vmcnt(0)" ::: "memory"); }
__device__ __forceinline__ void memfence() { asm volatile("" ::: "memory"); }

// ---------------------------------------------------------------------------
// fp32 -> bf16 bulk convert; Wq pre-scaled by 0.125*log2(e) (exp2 domain).
// ---------------------------------------------------------------------------
struct CvtArgs {
    const float* s[7];
    u16* d[7];
    float scale[7];
    int start[8];
};
__global__ __launch_bounds__(256) void cvt_kernel(CvtArgs a) {
    int bid = blockIdx.x;
    int seg = 0;
#pragma unroll
    for (int i = 1; i < 7; ++i) if (bid >= a.start[i]) seg = i;
    float sc = a.scale[seg];
    size_t base = (size_t)(bid - a.start[seg]) * 2048 + threadIdx.x * 8;
    const float4* s4 = (const float4*)(a.s[seg] + base);
    float4 x = s4[0], y = s4[1];
    u32 r[4];
    r[0] = pk2bf(x.x*sc, x.y*sc); r[1] = pk2bf(x.z*sc, x.w*sc);
    r[2] = pk2bf(y.x*sc, y.y*sc); r[3] = pk2bf(y.z*sc, y.w*sc);
    *(uint4*)(a.d[seg] + base) = *(uint4*)r;
}

// ---------------------------------------------------------------------------
// mask -> bits; word = bits[(b*2048+m)*64 + n/32]
// ---------------------------------------------------------------------------
__global__ void maskpack_kernel(const int* __restrict__ mask,
                                unsigned int* __restrict__ bits) {
    int gid = blockIdx.x * 256 + threadIdx.x;
    int m = mask[gid];
    unsigned long long bal = __ballot(m != 0);
    int lane = threadIdx.x & 63;
    if (lane == 0)       bits[gid >> 5] = (u32)(bal & 0xFFFFFFFFull);
    else if (lane == 32) bits[gid >> 5] = (u32)(bal >> 32);
}

// ---------------------------------------------------------------------------
// bf16 GEMM: Y[r][c] = sum_k A[r][k]*B[c][k], K=1024, BK=32.
// Triple-buffered LDS, prefetch distance 2, raw-barrier pipeline (no vmcnt(0)
// drains inside the loop). XOR swizzle (4 chunks/row) for conflict-free b128.
// RT=4: 128x128 tile; RT=2: 64x128. 256 threads, waves 2x2.
// mode 0: bf16 (B,H,S,64); mode 1: bf16 (B,H,64,S); mode 2: fp32 row-major.
// ---------------------------------------------------------------------------
template<int RT>
__device__ __forceinline__ void gemm_body(const u16* __restrict__ A,
                                          const u16* __restrict__ Bm,
                                          void* __restrict__ Y,
                                          int rtile, int ctile, int mode,
                                          u16* sA, u16* sB) {
    constexpr int ABUF = RT * 32 * 32;          // u16 per A buffer
    constexpr int BBUF = 128 * 32;
    const int tid  = threadIdx.x;
    const int wv   = tid >> 6, lane = tid & 63;
    const int quad = lane >> 4, ln = lane & 15;
    const int wr   = wv >> 1,  wc  = wv & 1;

    const int lr4 = lane >> 2;                          // row in 16-row shot
    const int lcc = ((lane & 3) ^ ((lane >> 3) & 3)) * 8;  // swizzled src col

    const u16* gA[RT/2]; u16* lA[RT/2];
#pragma unroll
    for (int s = 0; s < RT/2; ++s) {
        int seg = wv * (RT/2) + s;
        gA[s] = A + (size_t)(rtile * (RT*32) + seg*16 + lr4) * 1024 + lcc;
        lA[s] = sA + seg * 512;
    }
    const u16* gB[2]; u16* lB[2];
#pragma unroll
    for (int s = 0; s < 2; ++s) {
        int seg = wv * 2 + s;
        gB[s] = Bm + (size_t)(ctile * 128 + seg*16 + lr4) * 1024 + lcc;
        lB[s] = sB + seg * 512;
    }

    f32x4 acc[RT][4];
#pragma unroll
    for (int i = 0; i < RT; ++i)
#pragma unroll
        for (int j = 0; j < 4; ++j) acc[i][j] = (f32x4){0.f,0.f,0.f,0.f};

    const int c0 = (quad ^ ((ln >> 1) & 3)) * 8;

    // prologue: stage kt=0 -> buf0, kt=1 -> buf1
#pragma unroll
    for (int s = 0; s < RT/2; ++s) gl_lds16(gA[s], lA[s]);
#pragma unroll
    for (int s = 0; s < 2; ++s)    gl_lds16(gB[s], lB[s]);
#pragma unroll
    for (int s = 0; s < RT/2; ++s) gl_lds16(gA[s] + 32, lA[s] + ABUF);
#pragma unroll
    for (int s = 0; s < 2; ++s)    gl_lds16(gB[s] + 32, lB[s] + BBUF);

    int bc = 0, bp = 2;
    for (int kt = 0; kt < 32; ++kt) {
        if (RT == 4) wbar_vm4(); else wbar_vm3();   // drain kt's loads only
        int pk = (kt + 2) & 31;                     // wrap keeps waitcnt uniform
#pragma unroll
        for (int s = 0; s < RT/2; ++s) gl_lds16(gA[s] + pk*32, lA[s] + bp*ABUF);
#pragma unroll
        for (int s = 0; s < 2; ++s)    gl_lds16(gB[s] + pk*32, lB[s] + bp*BBUF);

        const u16* sAb = sA + bc * ABUF;
        const u16* sBb = sB + bc * BBUF;
        bf16x8 af[RT], bfr[4];
#pragma unroll
        for (int rt = 0; rt < RT; ++rt)
            af[rt] = *(const bf16x8*)(sAb + (wr*(RT*16) + rt*16 + ln) * 32 + c0);
#pragma unroll
        for (int ct = 0; ct < 4; ++ct)
            bfr[ct] = *(const bf16x8*)(sBb + (wc*64 + ct*16 + ln) * 32 + c0);
#pragma unroll
        for (int rt = 0; rt < RT; ++rt)
#pragma unroll
            for (int ct = 0; ct < 4; ++ct)
                acc[rt][ct] = __builtin_amdgcn_mfma_f32_16x16x32_bf16(
                    af[rt], bfr[ct], acc[rt][ct], 0, 0, 0);

        bc = (bc == 2) ? 0 : bc + 1;
        bp = (bp == 2) ? 0 : bp + 1;
    }
    vm_drain();   // in-flight gl_lds must not land after LDS is reallocated

#pragma unroll
    for (int rt = 0; rt < RT; ++rt) {
#pragma unroll
        for (int ct = 0; ct < 4; ++ct) {
#pragma unroll
            for (int i = 0; i < 4; ++i) {
                int R = rtile*(RT*32) + wr*(RT*16) + rt*16 + quad*4 + i;
                int C = ctile*128 + wc*64 + ct*16 + ln;
                float val = acc[rt][ct][i];
                if (mode == 0) {
                    int b = R >> 11, s = R & 2047, h = C >> 6, d = C & 63;
                    ((u16*)Y)[((size_t)((b*NH + h) * SEQ + s) << 6) + d] = f2bf(val);
                } else if (mode == 1) {
                    int h = R >> 6, d = R & 63, b = C >> 11, n = C & 2047;
                    ((u16*)Y)[((size_t)((b*NH + h) * 64 + d) << 11) + n] = f2bf(val);
                } else {
                    ((float*)Y)[(size_t)R * 1024 + C] = val;
                }
            }
        }
    }
}

struct QKVArgs { const u16* A[3]; const u16* B[3]; u16* Y[3]; };

__global__ __launch_bounds__(256) void gemm_qkv(QKVArgs g) {
    __shared__ u16 sA[3 * 128 * 32];
    __shared__ u16 sB[3 * 128 * 32];
    int z = blockIdx.z;
    if (z == 2)
        gemm_body<4>(g.A[2], g.B[2], g.Y[2], blockIdx.y, blockIdx.x, 1, sA, sB);
    else
        gemm_body<4>(g.A[z], g.B[z], g.Y[z], blockIdx.x, blockIdx.y, 0, sA, sB);
}

__global__ __launch_bounds__(256) void gemm_out(const u16* __restrict__ A,
                                                const u16* __restrict__ Bm,
                                                float* __restrict__ Y) {
    __shared__ u16 sA[3 * 64 * 32];
    __shared__ u16 sB[3 * 128 * 32];
    gemm_body<2>(A, Bm, Y, blockIdx.x, blockIdx.y, 2, sA, sB);
}

// ---------------------------------------------------------------------------
// Flash attention v6: v4 (16 rows/wave, 512 thr) + software-pipelined PV.
// v5 post-mortem: cutting LDS reads 45% and conflicts 12x made it SLOWER ->
// LDS throughput was never the limiter. The ~33% no-issue gap is the serial
// in-iter chain QK -> exp -> P ds_write -> lgkm wait -> P ds_read -> PV.
// v6 defers PV by one tile: per iter {QK(nt); PV(nt-1); exp(nt)+Pwrite(nt)}.
// P write->read gap = one full iteration (latency hidden); all 18 MFMAs issue
// back-to-back before the VALU tail. P double-slab (2x18KB); K 2-buf (dist 1;
// reads are MFMA-consumed before barrier arrival, so no race), V 3-buf
// (consumed one iter late). LDS 77824B -> still 2 blocks/CU, 16 waves/CU.
// Per-iter VMEM = {K(nt+1), V(nt+1), mask(nt+2)} -> barrier at vmcnt(2)
// drains K(nt), V(nt-1), mask(nt); leaves the 2 newest in flight.
// ---------------------------------------------------------------------------
__global__ __launch_bounds__(512, 4) void attn_kernel(
    const u16* __restrict__ qw,
    const u16* __restrict__ kw,
    const u16* __restrict__ vt,
    const u32* __restrict__ mbits,
    u16* __restrict__ ctx) {

    constexpr int RSD   = 36;               // sP row stride in dwords (72 u16)
    constexpr int PSLAB = 8 * 16 * RSD;     // u32 per P slab (4608)
    __shared__ u16 sK[2 * 4096];            // 16 KB
    __shared__ u16 sV[3 * 4096];            // 24 KB
    __shared__ u32 sPd[2 * PSLAB];          // 36 KB

    const int mtile = blockIdx.x;           // 0..15 (128 m-rows each)
    const int bh    = blockIdx.y;           // 0..31
    const int b     = bh >> 4;
    const int tid   = threadIdx.x;
    const int wv    = tid >> 6, lane = tid & 63;
    const int quad  = lane >> 4, ln = lane & 15;
    const int m0    = mtile * 128;

    const size_t hbase = (size_t)bh * SEQ * 64;

    // Q fragments (B operand of S^T): rows m = m0 + wv*16 + ln
    bf16x8 qf[2];
    {
        const u16* qp = qw + hbase + (size_t)(m0 + wv*16 + ln) * 64 + quad*8;
        qf[0] = *(const bf16x8*)(qp);
        qf[1] = *(const bf16x8*)(qp + 32);
    }

    f32x4 o[4], lsum;
    lsum = (f32x4){0.f,0.f,0.f,0.f};
#pragma unroll
    for (int j = 0; j < 4; ++j) o[j] = (f32x4){0.f,0.f,0.f,0.f};

    bf16x8 ones;
#pragma unroll
    for (int i = 0; i < 8; ++i) ones[i] = (short)0x3F80;   // bf16 1.0

    const u32* mrow = mbits + (size_t)(b*SEQ + m0 + wv*16 + ln) * 64;

    // K/V staging: one 16B shot per thread per tile (512 thr x 16B = 8KB)
    const int lr = lane >> 3;
    const int lc = (lane & 7) ^ lr;                      // XOR-swizzled chunk
    const u16* gK = kw + hbase + (size_t)(wv*8 + lr) * 64 + lc*8;
    const u16* gV = vt + hbase + (size_t)(wv*8 + lr) * SEQ + lc*8;
    u16* lK = sK + wv * 512;
    u16* lV = sV + wv * 512;

    const int c0 = (quad ^ (ln & 7)) * 8;
    u32* sPbase = sPd + wv * 16 * RSD;
    const u16* sP16 = (const u16*)sPd;

    // prologue. Issue order is load-bearing for iter-0's vmcnt(2):
    // [wwA, K0, V0, wwB] -> vmcnt(2) leaves {V0, wwB}, drains {wwA, K0}.
    uint2 wwA = *(const uint2*)(mrow);
    memfence();
    gl_lds16(gK, lK);                       // K(0) -> Kbuf0
    memfence();
    gl_lds16(gV, lV);                       // V(0) -> Vbuf0
    memfence();
    uint2 wwB = *(const uint2*)(mrow + 2);

    int vwb = 1;    // V write buf at iter nt = (nt+1)%3
    int vpv = 2;    // V read (PV) buf at iter nt = (nt-1)%3 (unused at nt=0)

    for (int nt = 0; nt < SEQ / 64; ++nt) {
        wbar_vm2();                          // drain K(nt), V(nt-1), m(nt)
        const int kc  = nt & 1;
        const int pkv = (nt + 1) & 31;       // wrap keeps waitcnt uniform
        const int pm  = (nt + 2) & 31;
        gl_lds16(gK + (size_t)pkv * 4096, lK + (kc ^ 1) * 4096);
        memfence();
        gl_lds16(gV + pkv * 64,           lV + vwb * 4096);
        memfence();
        uint2 wwC = *(const uint2*)(mrow + pm * 2);

        // ---- QK on tile nt: S^T = K Q^T, D[row=quad*4+i -> n][col=ln -> m]
        const u16* sKb = sK + kc * 4096;
        f32x4 s4[4];
#pragma unroll
        for (int ct = 0; ct < 4; ++ct) {
            const u16* kp = sKb + (ct*16 + ln) * 64;
            bf16x8 k0 = *(const bf16x8*)(kp + c0);
            bf16x8 k1 = *(const bf16x8*)(kp + (c0 ^ 32));
            f32x4 z = (f32x4){0.f, 0.f, 0.f, 0.f};
            z = __builtin_amdgcn_mfma_f32_16x16x32_bf16(k0, qf[0], z, 0, 0, 0);
            z = __builtin_amdgcn_mfma_f32_16x16x32_bf16(k1, qf[1], z, 0, 0, 0);
            s4[ct] = z;
        }

        // ---- PV on tile nt-1 (P slab kc^1, V buf vpv); P is wave-private
        if (nt) {
            const u16* pp  = sP16 + (kc ^ 1) * (PSLAB * 2) + (wv*16 + ln) * 72;
            const u16* sVb = sV + vpv * 4096;
            bf16x8 pf0 = *(const bf16x8*)(pp + quad*8);
            bf16x8 pf1 = *(const bf16x8*)(pp + 32 + quad*8);
            lsum = __builtin_amdgcn_mfma_f32_16x16x32_bf16(pf0, ones, lsum, 0, 0, 0);
            lsum = __builtin_amdgcn_mfma_f32_16x16x32_bf16(pf1, ones, lsum, 0, 0, 0);
#pragma unroll
            for (int ct = 0; ct < 4; ++ct) {
                const u16* vp = sVb + (ct*16 + ln) * 64;
                bf16x8 v0 = *(const bf16x8*)(vp + c0);
                bf16x8 v1 = *(const bf16x8*)(vp + (c0 ^ 32));
                o[ct] = __builtin_amdgcn_mfma_f32_16x16x32_bf16(pf0, v0, o[ct], 0, 0, 0);
                o[ct] = __builtin_amdgcn_mfma_f32_16x16x32_bf16(pf1, v1, o[ct], 0, 0, 0);
            }
        }

        // ---- exp(nt) + P write into slab kc
        {
            u32* sPw = sPbase + kc * PSLAB;
            u32 l0 = ~(wwA.x >> (quad * 4));
            u32 l1 = ~(wwA.y >> (quad * 4));
#pragma unroll
            for (int ct = 0; ct < 4; ++ct) {
                u32 lsel = (ct & 2) ? l1 : l0;
                float p[4];
#pragma unroll
                for (int i = 0; i < 4; ++i)
                    p[i] = mask_exp2(s4[ct][i], lsel, (ct & 1) * 16 + i);
                uint2 pk;
                pk.x = pk2bf(p[0], p[1]);
                pk.y = pk2bf(p[2], p[3]);
                *(uint2*)(sPw + ln * RSD + ct*8 + quad*2) = pk;
            }
        }

        wwA = wwB; wwB = wwC;
        vwb = (vwb == 2) ? 0 : vwb + 1;
        vpv = (vpv == 2) ? 0 : vpv + 1;
    }
    vm_drain();   // V(31) may still be in flight; also pins trailing gl_lds

    // ---- final PV: tile 31 (slab 1, V buf 31%3 = 1); wave-private P
    {
        const u16* pp  = sP16 + 1 * (PSLAB * 2) + (wv*16 + ln) * 72;
        const u16* sVb = sV + 1 * 4096;
        bf16x8 pf0 = *(const bf16x8*)(pp + quad*8);
        bf16x8 pf1 = *(const bf16x8*)(pp + 32 + quad*8);
        lsum = __builtin_amdgcn_mfma_f32_16x16x32_bf16(pf0, ones, lsum, 0, 0, 0);
        lsum = __builtin_amdgcn_mfma_f32_16x16x32_bf16(pf1, ones, lsum, 0, 0, 0);
#pragma unroll
        for (int ct = 0; ct < 4; ++ct) {
            const u16* vp = sVb + (ct*16 + ln) * 64;
            bf16x8 v0 = *(const bf16x8*)(vp + c0);
            bf16x8 v1 = *(const bf16x8*)(vp + (c0 ^ 32));
            o[ct] = __builtin_amdgcn_mfma_f32_16x16x32_bf16(pf0, v0, o[ct], 0, 0, 0);
            o[ct] = __builtin_amdgcn_mfma_f32_16x16x32_bf16(pf1, v1, o[ct], 0, 0, 0);
        }
    }

#pragma unroll
    for (int i = 0; i < 4; ++i) {
        float inv = 1.f / lsum[i];
        int m = m0 + wv*16 + quad*4 + i;
        size_t base = ((size_t)(b * SEQ + m) << 10) + (bh & 15) * 64;
#pragma unroll
        for (int ct = 0; ct < 4; ++ct)
            ctx[base + ct*16 + ln] = f2bf(o[ct][i] * inv);
    }
}

// ---------------------------------------------------------------------------
extern "C" void kernel_launch(void* const* d_in, const int* in_sizes, int n_in,
                              void* d_out, int out_size, void* d_ws, size_t ws_size,
                              hipStream_t stream) {
    const float* q    = (const float*)d_in[0];
    const float* k    = (const float*)d_in[1];
    const float* v    = (const float*)d_in[2];
    const int*   mask = (const int*)d_in[3];
    const float* Wq   = (const float*)d_in[4];
    const float* Wk   = (const float*)d_in[5];
    const float* Wv   = (const float*)d_in[6];
    const float* Wo   = (const float*)d_in[7];
    float* out = (float*)d_out;

    char* ws = (char*)d_ws;
    const size_t SZH = (size_t)NB * SEQ * DM * 2;       // 8 MiB
    const size_t SZW = (size_t)DM * DM * 2;             // 2 MiB
    u16* qw   = (u16*)(ws);
    u16* kw   = (u16*)(ws + SZH);
    u16* vt   = (u16*)(ws + 2*SZH);
    u16* ctx  = (u16*)(ws + 3*SZH);
    u16* vb   = ctx;                                    // v bf16 (dead before ctx)
    u32* mbits= (u32*)(ws + 4*SZH);                     // 1 MiB
    u16* qb   = (u16*)(ws + 4*SZH + (1u<<20));
    u16* kb   = (u16*)(ws + 4*SZH + (1u<<20) + SZH);
    u16* Wqb  = (u16*)(ws + 4*SZH + (1u<<20) + 2*SZH);
    u16* Wkb  = (u16*)((char*)Wqb + SZW);
    u16* Wvb  = (u16*)((char*)Wqb + 2*SZW);
    u16* Wob  = (u16*)((char*)Wqb + 3*SZW);

    const float CSC = 0.18033688011112042f;             // 0.125 * log2(e)

    CvtArgs ca;
    ca.s[0]=q;  ca.d[0]=qb;  ca.scale[0]=1.f;
    ca.s[1]=k;  ca.d[1]=kb;  ca.scale[1]=1.f;
    ca.s[2]=v;  ca.d[2]=vb;  ca.scale[2]=1.f;
    ca.s[3]=Wq; ca.d[3]=Wqb; ca.scale[3]=CSC;
    ca.s[4]=Wk; ca.d[4]=Wkb; ca.scale[4]=1.f;
    ca.s[5]=Wv; ca.d[5]=Wvb; ca.scale[5]=1.f;
    ca.s[6]=Wo; ca.d[6]=Wob; ca.scale[6]=1.f;
    int st[8] = {0, 2048, 4096, 6144, 6656, 7168, 7680, 8192};
    for (int i = 0; i < 8; ++i) ca.start[i] = st[i];
    cvt_kernel<<<dim3(8192), dim3(256), 0, stream>>>(ca);

    maskpack_kernel<<<dim3(NB*SEQ*SEQ/256), dim3(256), 0, stream>>>(mask, mbits);

    QKVArgs ga;
    ga.A[0]=qb;  ga.B[0]=Wqb; ga.Y[0]=qw;
    ga.A[1]=kb;  ga.B[1]=Wkb; ga.Y[1]=kw;
    ga.A[2]=Wvb; ga.B[2]=vb;  ga.Y[2]=vt;
    gemm_qkv<<<dim3(32, 8, 3), dim3(256), 0, stream>>>(ga);

    attn_kernel<<<dim3(SEQ/128, NB*NH), dim3(512), 0, stream>>>(qw, kw, vt, mbits, ctx);

    gemm_out<<<dim3(64, 8), dim3(256), 0, stream>>>(ctx, Wob, out);
}